// Round 2
// baseline (318.242 us; speedup 1.0000x reference)
//
#include <hip/hip_runtime.h>

#define B_  4
#define NN_ 20
#define C_  128
#define H_  8
#define W_  32
#define P_  256      // H*W
#define GS_ 32
#define L_  1024     // GS*GS
#define K_  5120     // NN*P

// ---------------- ws layout (float elements) ----------------
// ind   : int   [B*L*NN]   @ 0         (81920)
// Kscal : float [B*L*NN]   @ 81920     (81920)
// Rc    : float [360*P]    @ 163840    (92160)
// Pc    : float [B*NN*P]   @ 256000    (20480)
// pano  : float [B*NN*2*P] @ 276480    (40960)
// ovmax : float [B*L]      @ 317440    (4096)
// ovmean: float [B*L]      @ 321536    (4096)
// Ft    : float [B*K*C]    @ 325632    (2621440)
// part  : float [4*B*L*C]  @ 2947072   (2097152)  -> total 19.3 MB

// ---- fused front-end A: pano (80 blk) + overhead (16 blk) + rays conv (360 blk)
__global__ __launch_bounds__(256) void k_fa(const float* __restrict__ feats,
                                            const float* __restrict__ over,
                                            const float* __restrict__ rays,
                                            const float* __restrict__ w1,
                                            const float* __restrict__ w2,
                                            const float* __restrict__ fw,
                                            float* __restrict__ pano,
                                            float* __restrict__ ovmax,
                                            float* __restrict__ ovmean,
                                            float* __restrict__ Rc) {
  __shared__ float s[3 * P_];
  int bid = blockIdx.x, tid = threadIdx.x;
  if (bid < 80) {
    int t = bid * 256 + tid;                     // B*NN*P = 20480
    int p = t & 255, bn = t >> 8;
    const float* src = feats + bn * C_ * P_ + p;
    float mx = -3.4e38f, sm = 0.f;
    #pragma unroll 8
    for (int c = 0; c < C_; ++c) { float v = src[c * P_]; mx = fmaxf(mx, v); sm += v; }
    pano[(bn * 2 + 0) * P_ + p] = mx;
    pano[(bn * 2 + 1) * P_ + p] = sm * (1.0f / 128.0f);
  } else if (bid < 96) {
    int t = (bid - 80) * 256 + tid;              // B*L = 4096
    int b = t >> 10, l = t & 1023;
    const float* src = over + b * C_ * L_ + l;
    float mx = -3.4e38f, sm = 0.f;
    #pragma unroll 8
    for (int c = 0; c < C_; ++c) { float v = src[c * L_]; mx = fmaxf(mx, v); sm += v; }
    ovmax[t] = mx; ovmean[t] = sm * (1.0f / 128.0f);
  } else {
    int a = bid - 96;                            // 360 angles
    #pragma unroll
    for (int c = 0; c < 3; ++c) s[c * P_ + tid] = rays[(a * 3 + c) * P_ + tid];
    __syncthreads();
    int y = tid >> 5, x = tid & 31;
    float acc1 = 0.f, acc2 = 0.f;
    #pragma unroll
    for (int c = 0; c < 3; ++c) {
      const float* sc  = s + c * P_;
      const float* w1c = w1 + (1 + c) * 9;
      const float* w2c = w2 + (1 + c) * 25;
      #pragma unroll
      for (int dy = 0; dy < 3; ++dy) { int yy = ((y + dy + 7) & 7) * 32;
        #pragma unroll
        for (int dx = 0; dx < 3; ++dx) { int xx = (x + dx + 31) & 31;
          acc1 += sc[yy + xx] * w1c[dy * 3 + dx]; } }
      #pragma unroll
      for (int dy = 0; dy < 5; ++dy) { int yy = ((y + dy + 6) & 7) * 32;
        #pragma unroll
        for (int dx = 0; dx < 5; ++dx) { int xx = (x + dx + 30) & 31;
          acc2 += sc[yy + xx] * w2c[dy * 5 + dx]; } }
    }
    Rc[a * P_ + tid] = fw[0] * acc1 + fw[1] * acc2;
  }
}

// ---- fused front-end B: pano conv (80 blk) + geo (320 blk) + feats transpose (320 blk)
__global__ __launch_bounds__(256) void k_fb(const float* __restrict__ pano,
                                            const float* __restrict__ bbox,
                                            const float* __restrict__ locs,
                                            const float* __restrict__ ovmax,
                                            const float* __restrict__ ovmean,
                                            const float* __restrict__ feats,
                                            const float* __restrict__ w1,
                                            const float* __restrict__ w2,
                                            const float* __restrict__ b1,
                                            const float* __restrict__ b2,
                                            const float* __restrict__ fw,
                                            const float* __restrict__ fb,
                                            float* __restrict__ Pc,
                                            int* __restrict__ ind,
                                            float* __restrict__ Kscal,
                                            float* __restrict__ Ft) {
  __shared__ float s[32 * 257];
  int bid = blockIdx.x, tid = threadIdx.x;
  if (bid < 80) {
    int bn = bid;
    s[tid]      = pano[(bn * 2 + 0) * P_ + tid];
    s[P_ + tid] = pano[(bn * 2 + 1) * P_ + tid];
    __syncthreads();
    int y = tid >> 5, x = tid & 31;
    float acc1 = 0.f, acc2 = 0.f;
    #pragma unroll
    for (int c = 0; c < 2; ++c) {
      const float* sc  = s + c * P_;
      const float* w1c = w1 + (4 + c) * 9;
      const float* w2c = w2 + (4 + c) * 25;
      #pragma unroll
      for (int dy = 0; dy < 3; ++dy) { int yy = ((y + dy + 7) & 7) * 32;
        #pragma unroll
        for (int dx = 0; dx < 3; ++dx) { int xx = (x + dx + 31) & 31;
          acc1 += sc[yy + xx] * w1c[dy * 3 + dx]; } }
      #pragma unroll
      for (int dy = 0; dy < 5; ++dy) { int yy = ((y + dy + 6) & 7) * 32;
        #pragma unroll
        for (int dx = 0; dx < 5; ++dx) { int xx = (x + dx + 30) & 31;
          acc2 += sc[yy + xx] * w2c[dy * 5 + dx]; } }
    }
    Pc[bn * P_ + tid] = fw[0] * acc1 + fw[1] * acc2;
  } else if (bid < 400) {
    int t = (bid - 80) * 256 + tid;              // B*L*NN = 81920
    int n = t % NN_;
    int r = t / NN_;                             // b*L + l
    int l = r & 1023, b = r >> 10;
    int i = l >> 5, j = l & 31;
    float y0 = bbox[b * 4 + 0], x0 = bbox[b * 4 + 1];
    float y1 = bbox[b * 4 + 2], x1 = bbox[b * 4 + 3];
    float gy = (i == 31) ? y1 : (y0 + ((y1 - y0) / 31.0f) * (float)i);
    float gx = (j == 31) ? x1 : (x0 + ((x1 - x0) / 31.0f) * (float)j);
    float d0 = gy - locs[(b * NN_ + n) * 2 + 0];
    float d1 = gx - locs[(b * NN_ + n) * 2 + 1];
    float D  = sqrtf(d0 * d0 + d1 * d1 + 1e-12f);
    float th = atan2f(d1, d0);
    if (th < 0.f) th += 6.283185307179586f;
    float deg = th * 57.29577951308232f;
    int di = (int)rintf(deg);
    if (di >= 360) di -= 360;
    float s10 = 0, s16 = 0, s17 = 0;
    #pragma unroll
    for (int q = 0; q < 9; ++q) { s10 += w1[q]; s16 += w1[54 + q]; s17 += w1[63 + q]; }
    float s20 = 0, s26 = 0, s27 = 0;
    #pragma unroll
    for (int q = 0; q < 25; ++q) { s20 += w2[q]; s26 += w2[150 + q]; s27 += w2[175 + q]; }
    float om = ovmax[r], oa = ovmean[r];
    ind[t]   = di;
    Kscal[t] = fw[0] * (D * s10 + om * s16 + oa * s17 + b1[0])
             + fw[1] * (D * s20 + om * s26 + oa * s27 + b2[0]) + fb[0];
  } else {
    int bb = bid - 400;                          // 320 = (b*NN+n)*4 + c-quarter
    int bn = bb >> 2, cq = bb & 3;
    int b = bn / NN_, n = bn % NN_;
    int c0 = cq * 32;
    #pragma unroll 4
    for (int cc = 0; cc < 32; ++cc)
      s[cc * 257 + tid] = feats[(bn * C_ + c0 + cc) * P_ + tid];
    __syncthreads();
    int c = tid & 31, p8 = tid >> 5;
    #pragma unroll 4
    for (int pp = 0; pp < 32; ++pp) {
      int p = pp * 8 + p8;
      Ft[((size_t)b * K_ + n * P_ + p) * C_ + c0 + c] = s[c * 257 + p];
    }
  }
}

// Per grid cell: assemble logits, softmax over (n,p)=5120, write fp32 attn.
__global__ __launch_bounds__(256) void k_soft(const float* __restrict__ Rc,
                                              const float* __restrict__ Pc,
                                              const float* __restrict__ Kscal,
                                              const int* __restrict__ ind,
                                              float* __restrict__ attn) {
  int bl = blockIdx.x;                           // b*L + l
  int b = bl >> 10;
  int tid = threadIdx.x;                         // pixel p
  __shared__ float sK[NN_];
  __shared__ int   sI[NN_];
  __shared__ float red[8];                       // [0..3]=max, [4..7]=sum
  if (tid < NN_) { sI[tid] = ind[bl * NN_ + tid]; sK[tid] = Kscal[bl * NN_ + tid]; }
  __syncthreads();
  float lg[NN_];
  #pragma unroll
  for (int n = 0; n < NN_; ++n)
    lg[n] = Rc[sI[n] * P_ + tid] + Pc[(b * NN_ + n) * P_ + tid] + sK[n];
  float m = -3.4e38f;
  #pragma unroll
  for (int n = 0; n < NN_; ++n) m = fmaxf(m, lg[n]);
  #pragma unroll
  for (int off = 32; off > 0; off >>= 1) m = fmaxf(m, __shfl_xor(m, off));
  if ((tid & 63) == 0) red[tid >> 6] = m;
  __syncthreads();
  m = fmaxf(fmaxf(red[0], red[1]), fmaxf(red[2], red[3]));
  float ssum = 0.f;
  #pragma unroll
  for (int n = 0; n < NN_; ++n) { lg[n] = expf(lg[n] - m); ssum += lg[n]; }
  #pragma unroll
  for (int off = 32; off > 0; off >>= 1) ssum += __shfl_xor(ssum, off);
  if ((tid & 63) == 0) red[4 + (tid >> 6)] = ssum;
  __syncthreads();
  float inv = 1.0f / ((red[4] + red[5]) + (red[6] + red[7]));
  #pragma unroll
  for (int n = 0; n < NN_; ++n)
    attn[((size_t)bl * NN_ + n) * P_ + tid] = lg[n] * inv;
}

// part[ks][b,l,c] = sum_{k in split ks} attn[b,l,k] * Ft[b,k,c]
// Grid 512 = 4b x 32 ltiles x 4 ksplits; 256 thr = 4 waves; block tile 32 l x 128 c.
// Wave w owns l = l0 + 8w + 0..7. Lane = (kq = lane>>4, cg = lane&15):
//   per 4-k step, lane handles k = kk+kq, channels cg*4..+3 and cg*4+64..+67.
//   -> 2 ds_read_b128 (8 l-weights, 4 distinct broadcast addrs/instr, conflict-free)
//      + 2 global dwordx4 (coalesced, zero dup) feed 64 FMAs.
// vs prev: 2x FMA per LDS instr AND per VMEM instr (LDS pipe was the 102us bottleneck).
// 4 kq-partials combined once at the end via shfl_xor over lane bits 4,5.
// Staging is register-prefetched (T14) so global latency hides under compute.
__global__ __launch_bounds__(256) void k_mm(const float* __restrict__ attn,
                                            const float* __restrict__ Ft,
                                            float* __restrict__ part) {
  __shared__ __align__(16) float sW[256 * 36];   // sW[k][l], stride 36 keeps b128 align
  int bid = blockIdx.x;
  int ks = bid & 3;
  int lt = (bid >> 2) & 31;
  int b  = bid >> 7;
  int l0 = lt << 5;                              // 32 l per block
  int kbase = ks * (K_ / 4);                     // 1280
  int tid = threadIdx.x;
  int w8 = (tid >> 6) << 3;                      // wave * 8 -> l offset
  int lane = tid & 63;
  int kq = lane >> 4;                            // 0..3 : k parity within 4-k step
  int c0 = (lane & 15) << 2;                     // c 0..60 (lo half), +64 (hi half)
  float4 aL[8], aH[8];
  #pragma unroll
  for (int r = 0; r < 8; ++r) {
    aL[r] = make_float4(0.f, 0.f, 0.f, 0.f);
    aH[r] = make_float4(0.f, 0.f, 0.f, 0.f);
  }
  const float* arow  = attn + ((size_t)b * L_ + l0) * K_ + kbase;
  const float* fbase = Ft + ((size_t)b * K_ + kbase + kq) * C_ + c0;
  float st[32];
  #pragma unroll
  for (int r = 0; r < 32; ++r) st[r] = arow[(size_t)r * K_ + tid];
  for (int kc0 = 0; kc0 < K_ / 4; kc0 += 256) {
    __syncthreads();                             // all waves done reading sW
    #pragma unroll
    for (int r = 0; r < 32; ++r) sW[tid * 36 + r] = st[r];   // sW[k=tid][l=r]
    __syncthreads();
    if (kc0 + 256 < K_ / 4) {
      #pragma unroll
      for (int r = 0; r < 32; ++r) st[r] = arow[(size_t)r * K_ + kc0 + 256 + tid];
    }
    const float* fp  = fbase + (size_t)kc0 * C_;
    const float* swk = sW + kq * 36 + w8;
    #pragma unroll 4
    for (int kk = 0; kk < 256; kk += 4) {
      float4 a0 = *(const float4*)(swk + kk * 36);
      float4 a1 = *(const float4*)(swk + kk * 36 + 4);
      float4 f0 = *(const float4*)(fp + (size_t)kk * C_);
      float4 f1 = *(const float4*)(fp + (size_t)kk * C_ + 64);
#define FMA8(r, wgt) \
      aL[r].x += (wgt) * f0.x; aL[r].y += (wgt) * f0.y; \
      aL[r].z += (wgt) * f0.z; aL[r].w += (wgt) * f0.w; \
      aH[r].x += (wgt) * f1.x; aH[r].y += (wgt) * f1.y; \
      aH[r].z += (wgt) * f1.z; aH[r].w += (wgt) * f1.w;
      FMA8(0, a0.x) FMA8(1, a0.y) FMA8(2, a0.z) FMA8(3, a0.w)
      FMA8(4, a1.x) FMA8(5, a1.y) FMA8(6, a1.z) FMA8(7, a1.w)
#undef FMA8
    }
  }
  // combine the 4 kq-partials (lane bits 4,5); all lanes end with full sums
#define RED2(v) { v += __shfl_xor(v, 16); v += __shfl_xor(v, 32); }
  #pragma unroll
  for (int r = 0; r < 8; ++r) {
    RED2(aL[r].x) RED2(aL[r].y) RED2(aL[r].z) RED2(aL[r].w)
    RED2(aH[r].x) RED2(aH[r].y) RED2(aH[r].z) RED2(aH[r].w)
  }
#undef RED2
  // kq-group g writes rows {2g, 2g+1}: 16 lanes x float4 = 256 B contiguous per store
  #pragma unroll
  for (int r = 0; r < 8; ++r) {
    if ((r >> 1) == kq) {
      float* pt = part + (size_t)ks * (B_ * L_ * C_)
                + ((size_t)b * L_ + l0 + w8 + r) * C_;
      *(float4*)(pt + c0)      = aL[r];
      *(float4*)(pt + c0 + 64) = aH[r];
    }
  }
}

// gf = part0 + part1 + part2 + part3  (float4, 131072 groups)
__global__ __launch_bounds__(256) void k_red(const float* __restrict__ part,
                                             float* __restrict__ gf) {
  int t = blockIdx.x * 256 + threadIdx.x;        // 131072
  const float4* p = (const float4*)part;
  float4 a = p[t], b = p[t + 131072], c = p[t + 262144], d = p[t + 393216];
  float4 o;
  o.x = (a.x + b.x) + (c.x + d.x);
  o.y = (a.y + b.y) + (c.y + d.y);
  o.z = (a.z + b.z) + (c.z + d.z);
  o.w = (a.w + b.w) + (c.w + d.w);
  ((float4*)gf)[t] = o;
}

extern "C" void kernel_launch(void* const* d_in, const int* in_sizes, int n_in,
                              void* d_out, int out_size, void* d_ws, size_t ws_size,
                              hipStream_t stream) {
  const float* bbox  = (const float*)d_in[0];
  const float* locs  = (const float*)d_in[1];
  const float* feats = (const float*)d_in[2];
  const float* over  = (const float*)d_in[3];
  const float* rays  = (const float*)d_in[4];
  const float* w1    = (const float*)d_in[5];
  const float* b1    = (const float*)d_in[6];
  const float* w2    = (const float*)d_in[7];
  const float* b2    = (const float*)d_in[8];
  const float* fw    = (const float*)d_in[9];
  const float* fb    = (const float*)d_in[10];

  float* ws     = (float*)d_ws;
  int*   ind    = (int*)ws;
  float* Kscal  = ws + 81920;
  float* Rc     = ws + 163840;
  float* Pc     = ws + 256000;
  float* pano   = ws + 276480;
  float* ovmax  = ws + 317440;
  float* ovmean = ws + 321536;
  float* Ft     = ws + 325632;
  float* part   = ws + 2947072;

  float* gf   = (float*)d_out;
  float* attn = gf + (B_ * L_ * C_);             // 20.97M floats

  k_fa  <<<456, 256, 0, stream>>>(feats, over, rays, w1, w2, fw,
                                  pano, ovmax, ovmean, Rc);
  k_fb  <<<720, 256, 0, stream>>>(pano, bbox, locs, ovmax, ovmean, feats,
                                  w1, w2, b1, b2, fw, fb, Pc, ind, Kscal, Ft);
  k_soft<<<4096, 256, 0, stream>>>(Rc, Pc, Kscal, ind, attn);
  k_mm  <<<512, 256, 0, stream>>>(attn, Ft, part);
  k_red <<<512, 256, 0, stream>>>(part, gf);
}

// Round 3
// 218.826 us; speedup vs baseline: 1.4543x; 1.4543x over previous
//
#include <hip/hip_runtime.h>

#define B_  4
#define NN_ 20
#define C_  128
#define H_  8
#define W_  32
#define P_  256      // H*W
#define GS_ 32
#define L_  1024     // GS*GS
#define K_  5120     // NN*P

// ---------------- ws layout (float elements) ----------------
// ind   : int   [B*L*NN]   @ 0         (81920)
// Kscal : float [B*L*NN]   @ 81920     (81920)
// Rc    : float [360*P]    @ 163840    (92160)
// Pc    : float [B*NN*P]   @ 256000    (20480)
// pano  : float [B*NN*2*P] @ 276480    (40960)
// ovmax : float [B*L]      @ 317440    (4096)
// ovmean: float [B*L]      @ 321536    (4096)
// Ft    : float [B*K*C]    @ 325632    (2621440)
// part  : float [4*B*L*C]  @ 2947072   (2097152)  -> total 19.3 MB

// ---- fused front-end A: pano (80 blk) + overhead (16 blk) + rays conv (360 blk)
__global__ __launch_bounds__(256) void k_fa(const float* __restrict__ feats,
                                            const float* __restrict__ over,
                                            const float* __restrict__ rays,
                                            const float* __restrict__ w1,
                                            const float* __restrict__ w2,
                                            const float* __restrict__ fw,
                                            float* __restrict__ pano,
                                            float* __restrict__ ovmax,
                                            float* __restrict__ ovmean,
                                            float* __restrict__ Rc) {
  __shared__ float s[3 * P_];
  int bid = blockIdx.x, tid = threadIdx.x;
  if (bid < 80) {
    int t = bid * 256 + tid;                     // B*NN*P = 20480
    int p = t & 255, bn = t >> 8;
    const float* src = feats + bn * C_ * P_ + p;
    float mx = -3.4e38f, sm = 0.f;
    #pragma unroll 8
    for (int c = 0; c < C_; ++c) { float v = src[c * P_]; mx = fmaxf(mx, v); sm += v; }
    pano[(bn * 2 + 0) * P_ + p] = mx;
    pano[(bn * 2 + 1) * P_ + p] = sm * (1.0f / 128.0f);
  } else if (bid < 96) {
    int t = (bid - 80) * 256 + tid;              // B*L = 4096
    int b = t >> 10, l = t & 1023;
    const float* src = over + b * C_ * L_ + l;
    float mx = -3.4e38f, sm = 0.f;
    #pragma unroll 8
    for (int c = 0; c < C_; ++c) { float v = src[c * L_]; mx = fmaxf(mx, v); sm += v; }
    ovmax[t] = mx; ovmean[t] = sm * (1.0f / 128.0f);
  } else {
    int a = bid - 96;                            // 360 angles
    #pragma unroll
    for (int c = 0; c < 3; ++c) s[c * P_ + tid] = rays[(a * 3 + c) * P_ + tid];
    __syncthreads();
    int y = tid >> 5, x = tid & 31;
    float acc1 = 0.f, acc2 = 0.f;
    #pragma unroll
    for (int c = 0; c < 3; ++c) {
      const float* sc  = s + c * P_;
      const float* w1c = w1 + (1 + c) * 9;
      const float* w2c = w2 + (1 + c) * 25;
      #pragma unroll
      for (int dy = 0; dy < 3; ++dy) { int yy = ((y + dy + 7) & 7) * 32;
        #pragma unroll
        for (int dx = 0; dx < 3; ++dx) { int xx = (x + dx + 31) & 31;
          acc1 += sc[yy + xx] * w1c[dy * 3 + dx]; } }
      #pragma unroll
      for (int dy = 0; dy < 5; ++dy) { int yy = ((y + dy + 6) & 7) * 32;
        #pragma unroll
        for (int dx = 0; dx < 5; ++dx) { int xx = (x + dx + 30) & 31;
          acc2 += sc[yy + xx] * w2c[dy * 5 + dx]; } }
    }
    Rc[a * P_ + tid] = fw[0] * acc1 + fw[1] * acc2;
  }
}

// ---- fused front-end B: pano conv (80 blk) + geo (320 blk) + feats transpose (320 blk)
__global__ __launch_bounds__(256) void k_fb(const float* __restrict__ pano,
                                            const float* __restrict__ bbox,
                                            const float* __restrict__ locs,
                                            const float* __restrict__ ovmax,
                                            const float* __restrict__ ovmean,
                                            const float* __restrict__ feats,
                                            const float* __restrict__ w1,
                                            const float* __restrict__ w2,
                                            const float* __restrict__ b1,
                                            const float* __restrict__ b2,
                                            const float* __restrict__ fw,
                                            const float* __restrict__ fb,
                                            float* __restrict__ Pc,
                                            int* __restrict__ ind,
                                            float* __restrict__ Kscal,
                                            float* __restrict__ Ft) {
  __shared__ float s[32 * 257];
  int bid = blockIdx.x, tid = threadIdx.x;
  if (bid < 80) {
    int bn = bid;
    s[tid]      = pano[(bn * 2 + 0) * P_ + tid];
    s[P_ + tid] = pano[(bn * 2 + 1) * P_ + tid];
    __syncthreads();
    int y = tid >> 5, x = tid & 31;
    float acc1 = 0.f, acc2 = 0.f;
    #pragma unroll
    for (int c = 0; c < 2; ++c) {
      const float* sc  = s + c * P_;
      const float* w1c = w1 + (4 + c) * 9;
      const float* w2c = w2 + (4 + c) * 25;
      #pragma unroll
      for (int dy = 0; dy < 3; ++dy) { int yy = ((y + dy + 7) & 7) * 32;
        #pragma unroll
        for (int dx = 0; dx < 3; ++dx) { int xx = (x + dx + 31) & 31;
          acc1 += sc[yy + xx] * w1c[dy * 3 + dx]; } }
      #pragma unroll
      for (int dy = 0; dy < 5; ++dy) { int yy = ((y + dy + 6) & 7) * 32;
        #pragma unroll
        for (int dx = 0; dx < 5; ++dx) { int xx = (x + dx + 30) & 31;
          acc2 += sc[yy + xx] * w2c[dy * 5 + dx]; } }
    }
    Pc[bn * P_ + tid] = fw[0] * acc1 + fw[1] * acc2;
  } else if (bid < 400) {
    int t = (bid - 80) * 256 + tid;              // B*L*NN = 81920
    int n = t % NN_;
    int r = t / NN_;                             // b*L + l
    int l = r & 1023, b = r >> 10;
    int i = l >> 5, j = l & 31;
    float y0 = bbox[b * 4 + 0], x0 = bbox[b * 4 + 1];
    float y1 = bbox[b * 4 + 2], x1 = bbox[b * 4 + 3];
    float gy = (i == 31) ? y1 : (y0 + ((y1 - y0) / 31.0f) * (float)i);
    float gx = (j == 31) ? x1 : (x0 + ((x1 - x0) / 31.0f) * (float)j);
    float d0 = gy - locs[(b * NN_ + n) * 2 + 0];
    float d1 = gx - locs[(b * NN_ + n) * 2 + 1];
    float D  = sqrtf(d0 * d0 + d1 * d1 + 1e-12f);
    float th = atan2f(d1, d0);
    if (th < 0.f) th += 6.283185307179586f;
    float deg = th * 57.29577951308232f;
    int di = (int)rintf(deg);
    if (di >= 360) di -= 360;
    float s10 = 0, s16 = 0, s17 = 0;
    #pragma unroll
    for (int q = 0; q < 9; ++q) { s10 += w1[q]; s16 += w1[54 + q]; s17 += w1[63 + q]; }
    float s20 = 0, s26 = 0, s27 = 0;
    #pragma unroll
    for (int q = 0; q < 25; ++q) { s20 += w2[q]; s26 += w2[150 + q]; s27 += w2[175 + q]; }
    float om = ovmax[r], oa = ovmean[r];
    ind[t]   = di;
    Kscal[t] = fw[0] * (D * s10 + om * s16 + oa * s17 + b1[0])
             + fw[1] * (D * s20 + om * s26 + oa * s27 + b2[0]) + fb[0];
  } else {
    int bb = bid - 400;                          // 320 = (b*NN+n)*4 + c-quarter
    int bn = bb >> 2, cq = bb & 3;
    int b = bn / NN_, n = bn % NN_;
    int c0 = cq * 32;
    #pragma unroll 4
    for (int cc = 0; cc < 32; ++cc)
      s[cc * 257 + tid] = feats[(bn * C_ + c0 + cc) * P_ + tid];
    __syncthreads();
    int c = tid & 31, p8 = tid >> 5;
    #pragma unroll 4
    for (int pp = 0; pp < 32; ++pp) {
      int p = pp * 8 + p8;
      Ft[((size_t)b * K_ + n * P_ + p) * C_ + c0 + c] = s[c * 257 + p];
    }
  }
}

// Per grid cell: assemble logits, softmax over (n,p)=5120, write fp32 attn.
__global__ __launch_bounds__(256) void k_soft(const float* __restrict__ Rc,
                                              const float* __restrict__ Pc,
                                              const float* __restrict__ Kscal,
                                              const int* __restrict__ ind,
                                              float* __restrict__ attn) {
  int bl = blockIdx.x;                           // b*L + l
  int b = bl >> 10;
  int tid = threadIdx.x;                         // pixel p
  __shared__ float sK[NN_];
  __shared__ int   sI[NN_];
  __shared__ float red[8];                       // [0..3]=max, [4..7]=sum
  if (tid < NN_) { sI[tid] = ind[bl * NN_ + tid]; sK[tid] = Kscal[bl * NN_ + tid]; }
  __syncthreads();
  float lg[NN_];
  #pragma unroll
  for (int n = 0; n < NN_; ++n)
    lg[n] = Rc[sI[n] * P_ + tid] + Pc[(b * NN_ + n) * P_ + tid] + sK[n];
  float m = -3.4e38f;
  #pragma unroll
  for (int n = 0; n < NN_; ++n) m = fmaxf(m, lg[n]);
  #pragma unroll
  for (int off = 32; off > 0; off >>= 1) m = fmaxf(m, __shfl_xor(m, off));
  if ((tid & 63) == 0) red[tid >> 6] = m;
  __syncthreads();
  m = fmaxf(fmaxf(red[0], red[1]), fmaxf(red[2], red[3]));
  float ssum = 0.f;
  #pragma unroll
  for (int n = 0; n < NN_; ++n) { lg[n] = expf(lg[n] - m); ssum += lg[n]; }
  #pragma unroll
  for (int off = 32; off > 0; off >>= 1) ssum += __shfl_xor(ssum, off);
  if ((tid & 63) == 0) red[4 + (tid >> 6)] = ssum;
  __syncthreads();
  float inv = 1.0f / ((red[4] + red[5]) + (red[6] + red[7]));
  #pragma unroll
  for (int n = 0; n < NN_; ++n)
    attn[((size_t)bl * NN_ + n) * P_ + tid] = lg[n] * inv;
}

// part[ks][b,l,c] = sum_{k in split ks} attn[b,l,k] * Ft[b,k,c]
// Grid 512 = 4b x 32 ltiles x 4 ksplits; 256 thr = 4 waves; block tile 32 l x 128 c.
// Wave w owns l = l0 + 8w + 0..7. Lane = (h = lane>>5, cg = lane&31):
//   half-wave h handles k parity h; lane channels c0 = cg*4 (32 lanes x 4c = 128c).
//   Per 2-k step per wave: 2 ds_read_b128 (weights; 2 distinct broadcast addrs,
//   banks disjoint -> conflict-free) + 1 global dwordx4 (1KB = Ft rows k,k+1
//   contiguous, zero dup) feed 32 FMA/thread.
// vs r1: half the LDS-read instrs (the 102us bottleneck), same VMEM bytes.
// vs r2: acc = 32 VGPR (not 64), no register prefetch array -> no scratch spill.
// h-parity partials combined once at the end via shfl_xor(32).
__global__ __launch_bounds__(256) void k_mm(const float* __restrict__ attn,
                                            const float* __restrict__ Ft,
                                            float* __restrict__ part) {
  __shared__ __align__(16) float sW[256 * 36];   // sW[k][l], stride 36 keeps b128 align
  int bid = blockIdx.x;
  int ks = bid & 3;
  int lt = (bid >> 2) & 31;
  int b  = bid >> 7;
  int l0 = lt << 5;                              // 32 l per block
  int kbase = ks * (K_ / 4);                     // 1280
  int tid = threadIdx.x;
  int w8 = (tid >> 6) << 3;                      // wave * 8 -> l offset
  int lane = tid & 63;
  int h  = lane >> 5;                            // k parity
  int c0 = (lane & 31) << 2;                     // c 0..124
  float4 acc[8];
  #pragma unroll
  for (int r = 0; r < 8; ++r) acc[r] = make_float4(0.f, 0.f, 0.f, 0.f);
  const float* arow  = attn + ((size_t)b * L_ + l0) * K_ + kbase;
  const float* fbase = Ft + ((size_t)b * K_ + kbase + h) * C_ + c0;
  for (int kc0 = 0; kc0 < K_ / 4; kc0 += 256) {
    __syncthreads();                             // all waves done reading sW
    #pragma unroll
    for (int r = 0; r < 32; ++r)
      sW[tid * 36 + r] = arow[(size_t)r * K_ + kc0 + tid];   // sW[k=tid][l=r]
    __syncthreads();
    const float* fp  = fbase + (size_t)kc0 * C_;
    const float* swk = sW + h * 36 + w8;
    #pragma unroll 4
    for (int kk = 0; kk < 256; kk += 2) {
      float4 w03 = *(const float4*)(swk + kk * 36);       // k=kk+h, l=w8..w8+3
      float4 w47 = *(const float4*)(swk + kk * 36 + 4);   // l=w8+4..w8+7
      float4 f   = *(const float4*)(fp + (size_t)kk * C_);
      acc[0].x += w03.x * f.x; acc[0].y += w03.x * f.y;
      acc[0].z += w03.x * f.z; acc[0].w += w03.x * f.w;
      acc[1].x += w03.y * f.x; acc[1].y += w03.y * f.y;
      acc[1].z += w03.y * f.z; acc[1].w += w03.y * f.w;
      acc[2].x += w03.z * f.x; acc[2].y += w03.z * f.y;
      acc[2].z += w03.z * f.z; acc[2].w += w03.z * f.w;
      acc[3].x += w03.w * f.x; acc[3].y += w03.w * f.y;
      acc[3].z += w03.w * f.z; acc[3].w += w03.w * f.w;
      acc[4].x += w47.x * f.x; acc[4].y += w47.x * f.y;
      acc[4].z += w47.x * f.z; acc[4].w += w47.x * f.w;
      acc[5].x += w47.y * f.x; acc[5].y += w47.y * f.y;
      acc[5].z += w47.y * f.z; acc[5].w += w47.y * f.w;
      acc[6].x += w47.z * f.x; acc[6].y += w47.z * f.y;
      acc[6].z += w47.z * f.z; acc[6].w += w47.z * f.w;
      acc[7].x += w47.w * f.x; acc[7].y += w47.w * f.y;
      acc[7].z += w47.w * f.z; acc[7].w += w47.w * f.w;
    }
  }
  // combine even/odd-k partials across the half-wave split (lane bit 5)
  #pragma unroll
  for (int r = 0; r < 8; ++r) {
    acc[r].x += __shfl_xor(acc[r].x, 32);
    acc[r].y += __shfl_xor(acc[r].y, 32);
    acc[r].z += __shfl_xor(acc[r].z, 32);
    acc[r].w += __shfl_xor(acc[r].w, 32);
  }
  // h=0 writes rows 0..3, h=1 rows 4..7: each store instr = 2 rows x 512B, coalesced
  #pragma unroll
  for (int r = 0; r < 8; ++r) {
    if ((r >> 2) == h) {
      float* pt = part + (size_t)ks * (B_ * L_ * C_)
                + ((size_t)b * L_ + l0 + w8 + r) * C_ + c0;
      *(float4*)pt = acc[r];
    }
  }
}

// gf = part0 + part1 + part2 + part3  (float4, 131072 groups)
__global__ __launch_bounds__(256) void k_red(const float* __restrict__ part,
                                             float* __restrict__ gf) {
  int t = blockIdx.x * 256 + threadIdx.x;        // 131072
  const float4* p = (const float4*)part;
  float4 a = p[t], b = p[t + 131072], c = p[t + 262144], d = p[t + 393216];
  float4 o;
  o.x = (a.x + b.x) + (c.x + d.x);
  o.y = (a.y + b.y) + (c.y + d.y);
  o.z = (a.z + b.z) + (c.z + d.z);
  o.w = (a.w + b.w) + (c.w + d.w);
  ((float4*)gf)[t] = o;
}

extern "C" void kernel_launch(void* const* d_in, const int* in_sizes, int n_in,
                              void* d_out, int out_size, void* d_ws, size_t ws_size,
                              hipStream_t stream) {
  const float* bbox  = (const float*)d_in[0];
  const float* locs  = (const float*)d_in[1];
  const float* feats = (const float*)d_in[2];
  const float* over  = (const float*)d_in[3];
  const float* rays  = (const float*)d_in[4];
  const float* w1    = (const float*)d_in[5];
  const float* b1    = (const float*)d_in[6];
  const float* w2    = (const float*)d_in[7];
  const float* b2    = (const float*)d_in[8];
  const float* fw    = (const float*)d_in[9];
  const float* fb    = (const float*)d_in[10];

  float* ws     = (float*)d_ws;
  int*   ind    = (int*)ws;
  float* Kscal  = ws + 81920;
  float* Rc     = ws + 163840;
  float* Pc     = ws + 256000;
  float* pano   = ws + 276480;
  float* ovmax  = ws + 317440;
  float* ovmean = ws + 321536;
  float* Ft     = ws + 325632;
  float* part   = ws + 2947072;

  float* gf   = (float*)d_out;
  float* attn = gf + (B_ * L_ * C_);             // 20.97M floats

  k_fa  <<<456, 256, 0, stream>>>(feats, over, rays, w1, w2, fw,
                                  pano, ovmax, ovmean, Rc);
  k_fb  <<<720, 256, 0, stream>>>(pano, bbox, locs, ovmax, ovmean, feats,
                                  w1, w2, b1, b2, fw, fb, Pc, ind, Kscal, Ft);
  k_soft<<<4096, 256, 0, stream>>>(Rc, Pc, Kscal, ind, attn);
  k_mm  <<<512, 256, 0, stream>>>(attn, Ft, part);
  k_red <<<512, 256, 0, stream>>>(part, gf);
}